// Round 6
// baseline (382.054 us; speedup 1.0000x reference)
//
#include <hip/hip_runtime.h>
#include <hip/hip_fp16.h>

#define N_NODES 50000
#define N_EDGES 800000
#define EDIM 16
#define NEG_SLOPE 0.2f

// ============================ CSR build ============================
__global__ void count_kernel(const int* __restrict__ ei, int* __restrict__ cnt) {
    int e = blockIdx.x * blockDim.x + threadIdx.x;
    if (e < N_EDGES) atomicAdd(&cnt[ei[N_EDGES + e]], 1);
}

__global__ void scan_block_kernel(const int* __restrict__ in, int* __restrict__ excl,
                                  int* __restrict__ bsums, int n) {
    __shared__ int sh[256];
    int tid = threadIdx.x;
    int gid = blockIdx.x * 256 + tid;
    int v = (gid < n) ? in[gid] : 0;
    sh[tid] = v;
    __syncthreads();
    for (int off = 1; off < 256; off <<= 1) {
        int t = (tid >= off) ? sh[tid - off] : 0;
        __syncthreads();
        sh[tid] += t;
        __syncthreads();
    }
    if (gid < n) excl[gid] = sh[tid] - v;
    if (bsums != nullptr && tid == 255) bsums[blockIdx.x] = sh[tid];
}

__global__ void scan_add_kernel(const int* __restrict__ excl, const int* __restrict__ bs2,
                                int* __restrict__ csr_off, int* __restrict__ cursor,
                                int n, int total) {
    int gid = blockIdx.x * 256 + threadIdx.x;
    if (gid < n) {
        int v = excl[gid] + bs2[gid >> 8];
        csr_off[gid] = v;
        cursor[gid] = v;
    }
    if (gid == 0) csr_off[n] = total;
}

// writes CSR edge id, CSR src node, and edge->CSR-slot map
__global__ void scatter_kernel(const int* __restrict__ ei, int* __restrict__ cursor,
                               int* __restrict__ csr_eid, int* __restrict__ csr_src,
                               int* __restrict__ epos) {
    int e = blockIdx.x * blockDim.x + threadIdx.x;
    if (e < N_EDGES) {
        int s = ei[e];
        int d = ei[N_EDGES + e];
        int pos = atomicAdd(&cursor[d], 1);
        csr_eid[pos] = e;
        csr_src[pos] = s;
        epos[e] = pos;
    }
}

// ============================ shared precompute ============================
// w_e[h*16+d] = sum_c We[d][h*64+c] * ae[h][c]
__global__ void we_kernel(const float* __restrict__ We, const float* __restrict__ ae,
                          float* __restrict__ w_e) {
    int idx = threadIdx.x;
    if (idx >= 32) return;
    int h = idx >> 4, d = idx & 15;
    float s = 0.f;
    for (int c = 0; c < 64; ++c) s += We[d * 128 + h * 64 + c] * ae[h * 64 + c];
    w_e[idx] = s;
}

// per-edge attention-edge dots for BOTH layers: a_e4[k] = {l1h0, l1h1, l2h0, l2h1}
__global__ void edge_dot_kernel(const float* __restrict__ edge_attr,
                                const float* __restrict__ we1, const float* __restrict__ we2,
                                float4* __restrict__ a_e4) {
    int k = blockIdx.x * blockDim.x + threadIdx.x;
    if (k >= N_EDGES) return;
    float4 d = make_float4(0.f, 0.f, 0.f, 0.f);
#pragma unroll
    for (int q = 0; q < 4; ++q) {
        float4 v = *reinterpret_cast<const float4*>(edge_attr + (size_t)k * 16 + q * 4);
        float4 wa = *reinterpret_cast<const float4*>(we1 + q * 4);
        float4 wb = *reinterpret_cast<const float4*>(we1 + 16 + q * 4);
        float4 wc = *reinterpret_cast<const float4*>(we2 + q * 4);
        float4 wd = *reinterpret_cast<const float4*>(we2 + 16 + q * 4);
        d.x += v.x * wa.x + v.y * wa.y + v.z * wa.z + v.w * wa.w;
        d.y += v.x * wb.x + v.y * wb.y + v.z * wb.z + v.w * wb.w;
        d.z += v.x * wc.x + v.y * wc.y + v.z * wc.z + v.w * wc.w;
        d.w += v.x * wd.x + v.y * wd.y + v.z * wd.z + v.w * wd.w;
    }
    a_e4[k] = d;
}

// self-loop edge dot = mean of incoming edges' dots (linearity of dot vs mean attr)
__global__ void self_mean_kernel(const float4* __restrict__ a_e4, const int* __restrict__ csr_off,
                                 const int* __restrict__ csr_eid, float4* __restrict__ ae_self) {
    int n = blockIdx.x * blockDim.x + threadIdx.x;
    if (n >= N_NODES) return;
    int b = csr_off[n], e = csr_off[n + 1];
    float4 s = make_float4(0.f, 0.f, 0.f, 0.f);
    for (int j = b; j < e; ++j) {
        float4 v = a_e4[csr_eid[j]];
        s.x += v.x; s.y += v.y; s.z += v.z; s.w += v.w;
    }
    float inv = 1.f / (float)((e - b) > 0 ? (e - b) : 1);
    s.x *= inv; s.y *= inv; s.z *= inv; s.w *= inv;
    ae_self[n] = s;
}

// ============================ per-layer ============================
// C[M,128] = X[M,K] @ W[K,128]; also writes fp16 copy for the gather kernel
__global__ __launch_bounds__(256) void sgemm_kernel(const float* __restrict__ X,
                                                    const float* __restrict__ W,
                                                    float* __restrict__ Hout,
                                                    __half* __restrict__ H16, int M, int K) {
    __shared__ float xs[128 * 132];
    __shared__ float ws[128 * 132];
    const int tid = threadIdx.x;
    const int row0 = blockIdx.x * 128;
    const int xstride = K + 4;

    for (int q = tid; q < K * 32; q += 256) {
        int k = q >> 5, c4 = q & 31;
        float4 v = *reinterpret_cast<const float4*>(W + k * 128 + c4 * 4);
        *reinterpret_cast<float4*>(&ws[k * 132 + c4 * 4]) = v;
    }
    const int kshift = (K == 128) ? 5 : 4;
    const int kmask = (K >> 2) - 1;
    for (int q = tid; q < (128 << kshift); q += 256) {
        int r = q >> kshift, kq = q & kmask;
        int gr = row0 + r;
        float4 v = make_float4(0.f, 0.f, 0.f, 0.f);
        if (gr < M) v = *reinterpret_cast<const float4*>(X + (size_t)gr * K + kq * 4);
        *reinterpret_cast<float4*>(&xs[r * xstride + kq * 4]) = v;
    }
    __syncthreads();

    const int cg = tid & 15;
    const int rg = (tid >> 4) & 3;
    const int w = tid >> 6;
    const int rbase = w * 32 + rg;

    float acc[8][8];
#pragma unroll
    for (int i = 0; i < 8; ++i)
#pragma unroll
        for (int j = 0; j < 8; ++j) acc[i][j] = 0.f;

    for (int kk = 0; kk < K; kk += 4) {
        float4 a[8], b[8];
#pragma unroll
        for (int i = 0; i < 8; ++i)
            a[i] = *reinterpret_cast<const float4*>(&xs[(rbase + 4 * i) * xstride + kk]);
#pragma unroll
        for (int t = 0; t < 4; ++t) {
            b[t * 2] = *reinterpret_cast<const float4*>(&ws[(kk + t) * 132 + cg * 8]);
            b[t * 2 + 1] = *reinterpret_cast<const float4*>(&ws[(kk + t) * 132 + cg * 8 + 4]);
        }
#pragma unroll
        for (int t = 0; t < 4; ++t) {
            float bv[8];
            bv[0] = b[t * 2].x; bv[1] = b[t * 2].y; bv[2] = b[t * 2].z; bv[3] = b[t * 2].w;
            bv[4] = b[t * 2 + 1].x; bv[5] = b[t * 2 + 1].y; bv[6] = b[t * 2 + 1].z; bv[7] = b[t * 2 + 1].w;
#pragma unroll
            for (int i = 0; i < 8; ++i) {
                float av = (t == 0) ? a[i].x : (t == 1) ? a[i].y : (t == 2) ? a[i].z : a[i].w;
#pragma unroll
                for (int j = 0; j < 8; ++j) acc[i][j] = fmaf(av, bv[j], acc[i][j]);
            }
        }
    }
#pragma unroll
    for (int i = 0; i < 8; ++i) {
        int r = row0 + rbase + 4 * i;
        if (r < M) {
            float4 o0 = {acc[i][0], acc[i][1], acc[i][2], acc[i][3]};
            float4 o1 = {acc[i][4], acc[i][5], acc[i][6], acc[i][7]};
            *reinterpret_cast<float4*>(Hout + (size_t)r * 128 + cg * 8) = o0;
            *reinterpret_cast<float4*>(Hout + (size_t)r * 128 + cg * 8 + 4) = o1;
            __half t16[8];
#pragma unroll
            for (int j = 0; j < 8; ++j) t16[j] = __float2half_rn(acc[i][j]);
            *reinterpret_cast<float4*>(H16 + (size_t)r * 128 + cg * 8) =
                *reinterpret_cast<const float4*>(t16);
        }
    }
}

// a_src[n][h], a_dst[n][h]; one wave per node
__global__ void attdot_kernel(const float* __restrict__ Hb, const float* __restrict__ as,
                              const float* __restrict__ ad, float* __restrict__ a_src,
                              float* __restrict__ a_dst) {
    int wid = (blockIdx.x * blockDim.x + threadIdx.x) >> 6;
    int lane = threadIdx.x & 63;
    if (wid >= N_NODES) return;
    float h0 = Hb[(size_t)wid * 128 + lane];
    float h1 = Hb[(size_t)wid * 128 + 64 + lane];
    float s0 = h0 * as[lane], s1 = h1 * as[64 + lane];
    float d0 = h0 * ad[lane], d1 = h1 * ad[64 + lane];
#pragma unroll
    for (int m = 32; m; m >>= 1) {
        s0 += __shfl_xor(s0, m);
        s1 += __shfl_xor(s1, m);
        d0 += __shfl_xor(d0, m);
        d1 += __shfl_xor(d1, m);
    }
    if (lane == 0) {
        *reinterpret_cast<float2*>(a_src + wid * 2) = make_float2(s0, s1);
        *reinterpret_cast<float2*>(a_dst + wid * 2) = make_float2(d0, d1);
    }
}

// exp(leaky_relu(logit)); edges write into CSR order, self-loops into exl_self
__global__ void edge_logit_kernel(const int* __restrict__ ei,
                                  const float2* __restrict__ ae_pairs,      // a_e4 as float2[2E]
                                  const float2* __restrict__ ae_self_pairs, // ae_self as float2[2N]
                                  int layer,
                                  const float2* __restrict__ a_src, const float2* __restrict__ a_dst,
                                  const int* __restrict__ epos,
                                  float2* __restrict__ exl_csr, float2* __restrict__ exl_self) {
    int k = blockIdx.x * blockDim.x + threadIdx.x;
    if (k >= N_EDGES + N_NODES) return;
    float2 ae, asv, adv;
    if (k < N_EDGES) {
        int s = ei[k], d = ei[N_EDGES + k];
        ae = ae_pairs[2 * (size_t)k + layer];
        asv = a_src[s];
        adv = a_dst[d];
    } else {
        int n = k - N_EDGES;
        ae = ae_self_pairs[2 * (size_t)n + layer];
        asv = a_src[n];
        adv = a_dst[n];
    }
    float al0 = asv.x + adv.x + ae.x;
    float al1 = asv.y + adv.y + ae.y;
    al0 = (al0 > 0.f) ? al0 : NEG_SLOPE * al0;
    al1 = (al1 > 0.f) ? al1 : NEG_SLOPE * al1;
    float2 ex = make_float2(__expf(al0), __expf(al1));  // no max-shift: |alpha| small
    if (k < N_EDGES)
        exl_csr[epos[k]] = ex;
    else
        exl_self[k - N_EDGES] = ex;
}

// one wave per dst node; lane = channel; shfl-broadcast edge data; 3-deep gather pipeline
__global__ void aggregate_kernel(const int* __restrict__ csr_off, const int* __restrict__ csr_src,
                                 const float2* __restrict__ exl_csr,
                                 const float2* __restrict__ exl_self,
                                 const __half* __restrict__ H16, const float* __restrict__ bias,
                                 float* __restrict__ outp, int do_relu) {
    int wid = (blockIdx.x * blockDim.x + threadIdx.x) >> 6;
    int lane = threadIdx.x & 63;
    if (wid >= N_NODES) return;
    int n = wid;
    float2 exs = exl_self[n];
    float den0 = exs.x, den1 = exs.y;
    float acc0 = exs.x * __half2float(H16[(size_t)n * 128 + lane]);
    float acc1 = exs.y * __half2float(H16[(size_t)n * 128 + 64 + lane]);
    int b = csr_off[n], e = csr_off[n + 1];
    for (int base = b; base < e; base += 64) {
        int j = base + lane;
        int sv = 0;
        float2 exv = make_float2(0.f, 0.f);
        if (j < e) { sv = csr_src[j]; exv = exl_csr[j]; }
        int m = e - base;
        if (m > 64) m = 64;
        // 3-deep rotating prefetch (raw half regs; convert at consume)
        int s;
        __half p0a, p0b, p1a, p1b, p2a, p2b;
        s = __shfl(sv, 0);
        p0a = H16[(size_t)s * 128 + lane]; p0b = H16[(size_t)s * 128 + 64 + lane];
        s = __shfl(sv, 1);
        p1a = H16[(size_t)s * 128 + lane]; p1b = H16[(size_t)s * 128 + 64 + lane];
        s = __shfl(sv, 2);
        p2a = H16[(size_t)s * 128 + lane]; p2b = H16[(size_t)s * 128 + 64 + lane];
        for (int t = 0; t < m; ++t) {
            float ex0 = __shfl(exv.x, t);
            float ex1 = __shfl(exv.y, t);
            float g0 = __half2float(p0a);
            float g1 = __half2float(p0b);
            p0a = p1a; p0b = p1b;
            p1a = p2a; p1b = p2b;
            s = __shfl(sv, (t + 3) & 63);
            p2a = H16[(size_t)s * 128 + lane];
            p2b = H16[(size_t)s * 128 + 64 + lane];
            den0 += ex0; den1 += ex1;
            acc0 = fmaf(ex0, g0, acc0);
            acc1 = fmaf(ex1, g1, acc1);
        }
    }
    float r = 0.5f * (acc0 / (den0 + 1e-16f) + acc1 / (den1 + 1e-16f)) + bias[lane];
    if (do_relu) r = fmaxf(r, 0.f);
    outp[(size_t)n * 64 + lane] = r;
}

// ============================ launch ============================
extern "C" void kernel_launch(void* const* d_in, const int* in_sizes, int n_in,
                              void* d_out, int out_size, void* d_ws, size_t ws_size,
                              hipStream_t stream) {
    const float* x = (const float*)d_in[0];
    const int* ei = (const int*)d_in[1];
    const float* edge_attr = (const float*)d_in[2];
    const float* W1 = (const float*)d_in[3];
    const float* We1 = (const float*)d_in[4];
    const float* as1 = (const float*)d_in[5];
    const float* ad1 = (const float*)d_in[6];
    const float* ae1 = (const float*)d_in[7];
    const float* b1 = (const float*)d_in[8];
    const float* W2 = (const float*)d_in[9];
    const float* We2 = (const float*)d_in[10];
    const float* as2 = (const float*)d_in[11];
    const float* ad2 = (const float*)d_in[12];
    const float* ae2 = (const float*)d_in[13];
    const float* b2 = (const float*)d_in[14];
    float* out = (float*)d_out;

    char* ws = (char*)d_ws;
    size_t off = 0;
    auto alloc = [&](size_t bytes) -> void* {
        void* p = ws + off;
        off += (bytes + 255) & ~(size_t)255;
        return p;
    };
    int* cnt = (int*)alloc((size_t)N_NODES * 4);
    int* cursor = (int*)alloc((size_t)N_NODES * 4);
    int* csr_off = (int*)alloc(((size_t)N_NODES + 1) * 4);
    int* csr_eid = (int*)alloc((size_t)N_EDGES * 4);
    int* csr_src = (int*)alloc((size_t)N_EDGES * 4);
    int* epos = (int*)alloc((size_t)N_EDGES * 4);
    int* bsums = (int*)alloc(256 * 4);
    int* bsums2 = (int*)alloc(256 * 4);
    float* hbuf = (float*)alloc((size_t)N_NODES * 128 * 4);
    __half* H16 = (__half*)alloc((size_t)N_NODES * 128 * 2);
    float* h1 = (float*)alloc((size_t)N_NODES * 64 * 4);
    float* a_src = (float*)alloc((size_t)N_NODES * 2 * 4);
    float* a_dst = (float*)alloc((size_t)N_NODES * 2 * 4);
    float2* exl_csr = (float2*)alloc((size_t)N_EDGES * 8);
    float2* exl_self = (float2*)alloc((size_t)N_NODES * 8);
    float4* a_e4 = (float4*)alloc((size_t)N_EDGES * 16);
    float4* ae_self4 = (float4*)alloc((size_t)N_NODES * 16);
    float* w_e1 = (float*)alloc(32 * 4);
    float* w_e2 = (float*)alloc(32 * 4);

    const int nb = (N_NODES + 255) / 256;

    // ---- CSR + shared edge precompute ----
    hipMemsetAsync(cnt, 0, (size_t)N_NODES * 4, stream);
    count_kernel<<<(N_EDGES + 255) / 256, 256, 0, stream>>>(ei, cnt);
    scan_block_kernel<<<nb, 256, 0, stream>>>(cnt, cursor, bsums, N_NODES);
    scan_block_kernel<<<1, 256, 0, stream>>>(bsums, bsums2, nullptr, nb);
    scan_add_kernel<<<nb, 256, 0, stream>>>(cursor, bsums2, csr_off, cursor, N_NODES, N_EDGES);
    scatter_kernel<<<(N_EDGES + 255) / 256, 256, 0, stream>>>(ei, cursor, csr_eid, csr_src, epos);
    we_kernel<<<1, 64, 0, stream>>>(We1, ae1, w_e1);
    we_kernel<<<1, 64, 0, stream>>>(We2, ae2, w_e2);
    edge_dot_kernel<<<(N_EDGES + 255) / 256, 256, 0, stream>>>(edge_attr, w_e1, w_e2, a_e4);
    self_mean_kernel<<<(N_NODES + 255) / 256, 256, 0, stream>>>(a_e4, csr_off, csr_eid, ae_self4);

    const int nodeWaveBlocks = (N_NODES * 64 + 255) / 256;
    const int edgeBlocks = (N_EDGES + N_NODES + 255) / 256;
    const int gemmBlocks = (N_NODES + 127) / 128;

    // ---- layer 1: IN=128 -> HID=64, H=2, relu ----
    sgemm_kernel<<<gemmBlocks, 256, 0, stream>>>(x, W1, hbuf, H16, N_NODES, 128);
    attdot_kernel<<<nodeWaveBlocks, 256, 0, stream>>>(hbuf, as1, ad1, a_src, a_dst);
    edge_logit_kernel<<<edgeBlocks, 256, 0, stream>>>(ei, (const float2*)a_e4, (const float2*)ae_self4, 0,
                                                      (const float2*)a_src, (const float2*)a_dst,
                                                      epos, exl_csr, exl_self);
    aggregate_kernel<<<nodeWaveBlocks, 256, 0, stream>>>(csr_off, csr_src, exl_csr, exl_self, H16, b1, h1, 1);

    // ---- layer 2: HID=64 -> OUT=64, H=2, no relu ----
    sgemm_kernel<<<gemmBlocks, 256, 0, stream>>>(h1, W2, hbuf, H16, N_NODES, 64);
    attdot_kernel<<<nodeWaveBlocks, 256, 0, stream>>>(hbuf, as2, ad2, a_src, a_dst);
    edge_logit_kernel<<<edgeBlocks, 256, 0, stream>>>(ei, (const float2*)a_e4, (const float2*)ae_self4, 1,
                                                      (const float2*)a_src, (const float2*)a_dst,
                                                      epos, exl_csr, exl_self);
    aggregate_kernel<<<nodeWaveBlocks, 256, 0, stream>>>(csr_off, csr_src, exl_csr, exl_self, H16, b2, out, 0);
}

// Round 7
// 308.610 us; speedup vs baseline: 1.2380x; 1.2380x over previous
//
#include <hip/hip_runtime.h>

#define N_NODES 50000
#define N_EDGES 800000
#define EDIM 16
#define NEG_SLOPE 0.2f

typedef _Float16 f16x8 __attribute__((ext_vector_type(8)));
typedef float f32x4 __attribute__((ext_vector_type(4)));

// ============================ CSR build ============================
__global__ void count_kernel(const int* __restrict__ ei, int* __restrict__ cnt) {
    int e = blockIdx.x * blockDim.x + threadIdx.x;
    if (e < N_EDGES) atomicAdd(&cnt[ei[N_EDGES + e]], 1);
}

__global__ void scan_block_kernel(const int* __restrict__ in, int* __restrict__ excl,
                                  int* __restrict__ bsums, int n) {
    __shared__ int sh[256];
    int tid = threadIdx.x;
    int gid = blockIdx.x * 256 + tid;
    int v = (gid < n) ? in[gid] : 0;
    sh[tid] = v;
    __syncthreads();
    for (int off = 1; off < 256; off <<= 1) {
        int t = (tid >= off) ? sh[tid - off] : 0;
        __syncthreads();
        sh[tid] += t;
        __syncthreads();
    }
    if (gid < n) excl[gid] = sh[tid] - v;
    if (bsums != nullptr && tid == 255) bsums[blockIdx.x] = sh[tid];
}

__global__ void scan_add_kernel(const int* __restrict__ excl, const int* __restrict__ bs2,
                                int* __restrict__ csr_off, int* __restrict__ cursor,
                                int n, int total) {
    int gid = blockIdx.x * 256 + threadIdx.x;
    if (gid < n) {
        int v = excl[gid] + bs2[gid >> 8];
        csr_off[gid] = v;
        cursor[gid] = v;
    }
    if (gid == 0) csr_off[n] = total;
}

__global__ void scatter_kernel(const int* __restrict__ ei, int* __restrict__ cursor,
                               int* __restrict__ csr_eid, int* __restrict__ csr_src,
                               int* __restrict__ epos) {
    int e = blockIdx.x * blockDim.x + threadIdx.x;
    if (e < N_EDGES) {
        int s = ei[e];
        int d = ei[N_EDGES + e];
        int pos = atomicAdd(&cursor[d], 1);
        csr_eid[pos] = e;
        csr_src[pos] = s;
        epos[e] = pos;
    }
}

// ============================ shared precompute ============================
__global__ void we_kernel(const float* __restrict__ We, const float* __restrict__ ae,
                          float* __restrict__ w_e) {
    int idx = threadIdx.x;
    if (idx >= 32) return;
    int h = idx >> 4, d = idx & 15;
    float s = 0.f;
    for (int c = 0; c < 64; ++c) s += We[d * 128 + h * 64 + c] * ae[h * 64 + c];
    w_e[idx] = s;
}

__global__ void edge_dot_kernel(const float* __restrict__ edge_attr,
                                const float* __restrict__ we1, const float* __restrict__ we2,
                                float4* __restrict__ a_e4) {
    int k = blockIdx.x * blockDim.x + threadIdx.x;
    if (k >= N_EDGES) return;
    float4 d = make_float4(0.f, 0.f, 0.f, 0.f);
#pragma unroll
    for (int q = 0; q < 4; ++q) {
        float4 v = *reinterpret_cast<const float4*>(edge_attr + (size_t)k * 16 + q * 4);
        float4 wa = *reinterpret_cast<const float4*>(we1 + q * 4);
        float4 wb = *reinterpret_cast<const float4*>(we1 + 16 + q * 4);
        float4 wc = *reinterpret_cast<const float4*>(we2 + q * 4);
        float4 wd = *reinterpret_cast<const float4*>(we2 + 16 + q * 4);
        d.x += v.x * wa.x + v.y * wa.y + v.z * wa.z + v.w * wa.w;
        d.y += v.x * wb.x + v.y * wb.y + v.z * wb.z + v.w * wb.w;
        d.z += v.x * wc.x + v.y * wc.y + v.z * wc.z + v.w * wc.w;
        d.w += v.x * wd.x + v.y * wd.y + v.z * wd.z + v.w * wd.w;
    }
    a_e4[k] = d;
}

__global__ void self_mean_kernel(const float4* __restrict__ a_e4, const int* __restrict__ csr_off,
                                 const int* __restrict__ csr_eid, float4* __restrict__ ae_self) {
    int n = blockIdx.x * blockDim.x + threadIdx.x;
    if (n >= N_NODES) return;
    int b = csr_off[n], e = csr_off[n + 1];
    float4 s = make_float4(0.f, 0.f, 0.f, 0.f);
    for (int j = b; j < e; ++j) {
        float4 v = a_e4[csr_eid[j]];
        s.x += v.x; s.y += v.y; s.z += v.z; s.w += v.w;
    }
    float inv = 1.f / (float)((e - b) > 0 ? (e - b) : 1);
    s.x *= inv; s.y *= inv; s.z *= inv; s.w *= inv;
    ae_self[n] = s;
}

// ============================ f32 -> f16 cast (x only) ============================
__global__ void cast_f16_kernel(const float* __restrict__ in, _Float16* __restrict__ out, int n8) {
    int i = blockIdx.x * blockDim.x + threadIdx.x;
    if (i >= n8) return;
    float4 v0 = *reinterpret_cast<const float4*>(in + (size_t)i * 8);
    float4 v1 = *reinterpret_cast<const float4*>(in + (size_t)i * 8 + 4);
    _Float16 o[8] = {(_Float16)v0.x, (_Float16)v0.y, (_Float16)v0.z, (_Float16)v0.w,
                     (_Float16)v1.x, (_Float16)v1.y, (_Float16)v1.z, (_Float16)v1.w};
    *reinterpret_cast<float4*>(out + (size_t)i * 8) = *reinterpret_cast<const float4*>(o);
}

// ============================ fused MFMA GEMM + attdot ============================
// H = X16[M,K] @ W[K,128] (f16 in, f32 acc). Writes H16 and per-row attention dots.
// Wave = 16-row strip x 128 cols. Block = 4 waves = 64 rows.
// Layouts (guide §3, m89/m156): A: row=lane&15, k=8*(lane>>4)+j
//                               B: col=lane&15, k=8*(lane>>4)+j
//                               D: col=lane&15, row=4*(lane>>4)+reg
template <int K>
__global__ __launch_bounds__(256) void gemm_att_kernel(const _Float16* __restrict__ X16,
                                                       const float* __restrict__ W,
                                                       const float* __restrict__ as_,
                                                       const float* __restrict__ ad_,
                                                       _Float16* __restrict__ H16,
                                                       float2* __restrict__ a_src,
                                                       float2* __restrict__ a_dst, int M) {
    constexpr int NCH = K / 32;
    __shared__ _Float16 wlds[8 * NCH * 64 * 8];  // [ct][chunk][lane][j]
    const int tid = threadIdx.x;

    // stage W (f32 global, coalesced) -> wlds in fragment order, converting to f16
    for (int idx = tid; idx < K * 128; idx += 256) {
        int k = idx >> 7, c = idx & 127;
        int ct = c >> 4, cl = c & 15;
        int chunk = k >> 5, grp = (k >> 3) & 3, j = k & 7;
        wlds[(((ct * NCH) + chunk) * 64 + (grp * 16 + cl)) * 8 + j] = (_Float16)W[idx];
    }
    __syncthreads();

    const int wv = tid >> 6, lane = tid & 63;
    const int lcol = lane & 15, lgrp = lane >> 4;
    const int row0 = blockIdx.x * 64 + wv * 16;
    int arow = row0 + lcol;          // A-operand row for this lane
    if (arow >= M) arow = M - 1;     // clamp (stores are guarded)
    const _Float16* aptr = X16 + (size_t)arow * K + lgrp * 8;

    f32x4 acc[8];
#pragma unroll
    for (int ct = 0; ct < 8; ++ct) acc[ct] = (f32x4){0.f, 0.f, 0.f, 0.f};

#pragma unroll
    for (int chunk = 0; chunk < NCH; ++chunk) {
        f16x8 afrag = *reinterpret_cast<const f16x8*>(aptr + chunk * 32);
#pragma unroll
        for (int ct = 0; ct < 8; ++ct) {
            f16x8 bfrag = *reinterpret_cast<const f16x8*>(&wlds[((ct * NCH + chunk) * 64 + lane) * 8]);
            acc[ct] = __builtin_amdgcn_mfma_f32_16x16x32_f16(afrag, bfrag, acc[ct], 0, 0, 0);
        }
    }

    // attention vectors for this lane's column positions
    float asv[8], adv[8];
#pragma unroll
    for (int ct = 0; ct < 8; ++ct) {
        asv[ct] = as_[ct * 16 + lcol];
        adv[ct] = ad_[ct * 16 + lcol];
    }

#pragma unroll
    for (int r = 0; r < 4; ++r) {
        int grow = row0 + lgrp * 4 + r;  // D row
        // H16 store (f16) + per-row attention dot partials
        float s0 = 0.f, s1 = 0.f, d0 = 0.f, d1 = 0.f;
#pragma unroll
        for (int ct = 0; ct < 8; ++ct) {
            float v = acc[ct][r];
            if (grow < M) H16[(size_t)grow * 128 + ct * 16 + lcol] = (_Float16)v;
            if (ct < 4) { s0 += v * asv[ct]; d0 += v * adv[ct]; }
            else        { s1 += v * asv[ct]; d1 += v * adv[ct]; }
        }
        // reduce over the 16 lanes (same lgrp) that share this row
#pragma unroll
        for (int m = 1; m < 16; m <<= 1) {
            s0 += __shfl_xor(s0, m);
            s1 += __shfl_xor(s1, m);
            d0 += __shfl_xor(d0, m);
            d1 += __shfl_xor(d1, m);
        }
        if (lcol == 0 && grow < M) {
            a_src[grow] = make_float2(s0, s1);
            a_dst[grow] = make_float2(d0, d1);
        }
    }
}

// ============================ edge logits ============================
__global__ void edge_logit_kernel(const int* __restrict__ ei,
                                  const float2* __restrict__ ae_pairs,
                                  const float2* __restrict__ ae_self_pairs,
                                  int layer,
                                  const float2* __restrict__ a_src, const float2* __restrict__ a_dst,
                                  const int* __restrict__ epos,
                                  float2* __restrict__ exl_csr, float2* __restrict__ exl_self) {
    int k = blockIdx.x * blockDim.x + threadIdx.x;
    if (k >= N_EDGES + N_NODES) return;
    float2 ae, asv, adv;
    if (k < N_EDGES) {
        int s = ei[k], d = ei[N_EDGES + k];
        ae = ae_pairs[2 * (size_t)k + layer];
        asv = a_src[s];
        adv = a_dst[d];
    } else {
        int n = k - N_EDGES;
        ae = ae_self_pairs[2 * (size_t)n + layer];
        asv = a_src[n];
        adv = a_dst[n];
    }
    float al0 = asv.x + adv.x + ae.x;
    float al1 = asv.y + adv.y + ae.y;
    al0 = (al0 > 0.f) ? al0 : NEG_SLOPE * al0;
    al1 = (al1 > 0.f) ? al1 : NEG_SLOPE * al1;
    float2 ex = make_float2(__expf(al0), __expf(al1));  // no max-shift: |alpha| small
    if (k < N_EDGES)
        exl_csr[epos[k]] = ex;
    else
        exl_self[k - N_EDGES] = ex;
}

// ============================ aggregate ============================
// one wave per dst node; lane = channel; shfl-broadcast edge data; 3-deep gather pipeline
__global__ void aggregate_kernel(const int* __restrict__ csr_off, const int* __restrict__ csr_src,
                                 const float2* __restrict__ exl_csr,
                                 const float2* __restrict__ exl_self,
                                 const _Float16* __restrict__ H16, const float* __restrict__ bias,
                                 float* __restrict__ out32, _Float16* __restrict__ out16,
                                 int do_relu) {
    int wid = (blockIdx.x * blockDim.x + threadIdx.x) >> 6;
    int lane = threadIdx.x & 63;
    if (wid >= N_NODES) return;
    int n = wid;
    float2 exs = exl_self[n];
    float den0 = exs.x, den1 = exs.y;
    float acc0 = exs.x * (float)H16[(size_t)n * 128 + lane];
    float acc1 = exs.y * (float)H16[(size_t)n * 128 + 64 + lane];
    int b = csr_off[n], e = csr_off[n + 1];
    for (int base = b; base < e; base += 64) {
        int j = base + lane;
        int sv = 0;
        float2 exv = make_float2(0.f, 0.f);
        if (j < e) { sv = csr_src[j]; exv = exl_csr[j]; }
        int m = e - base;
        if (m > 64) m = 64;
        int s;
        _Float16 p0a, p0b, p1a, p1b, p2a, p2b;
        s = __shfl(sv, 0);
        p0a = H16[(size_t)s * 128 + lane]; p0b = H16[(size_t)s * 128 + 64 + lane];
        s = __shfl(sv, 1);
        p1a = H16[(size_t)s * 128 + lane]; p1b = H16[(size_t)s * 128 + 64 + lane];
        s = __shfl(sv, 2);
        p2a = H16[(size_t)s * 128 + lane]; p2b = H16[(size_t)s * 128 + 64 + lane];
        for (int t = 0; t < m; ++t) {
            float ex0 = __shfl(exv.x, t);
            float ex1 = __shfl(exv.y, t);
            float g0 = (float)p0a;
            float g1 = (float)p0b;
            p0a = p1a; p0b = p1b;
            p1a = p2a; p1b = p2b;
            s = __shfl(sv, (t + 3) & 63);
            p2a = H16[(size_t)s * 128 + lane];
            p2b = H16[(size_t)s * 128 + 64 + lane];
            den0 += ex0; den1 += ex1;
            acc0 = fmaf(ex0, g0, acc0);
            acc1 = fmaf(ex1, g1, acc1);
        }
    }
    float r = 0.5f * (acc0 / (den0 + 1e-16f) + acc1 / (den1 + 1e-16f)) + bias[lane];
    if (do_relu) r = fmaxf(r, 0.f);
    if (out32) out32[(size_t)n * 64 + lane] = r;
    if (out16) out16[(size_t)n * 64 + lane] = (_Float16)r;
}

// ============================ launch ============================
extern "C" void kernel_launch(void* const* d_in, const int* in_sizes, int n_in,
                              void* d_out, int out_size, void* d_ws, size_t ws_size,
                              hipStream_t stream) {
    const float* x = (const float*)d_in[0];
    const int* ei = (const int*)d_in[1];
    const float* edge_attr = (const float*)d_in[2];
    const float* W1 = (const float*)d_in[3];
    const float* We1 = (const float*)d_in[4];
    const float* as1 = (const float*)d_in[5];
    const float* ad1 = (const float*)d_in[6];
    const float* ae1 = (const float*)d_in[7];
    const float* b1 = (const float*)d_in[8];
    const float* W2 = (const float*)d_in[9];
    const float* We2 = (const float*)d_in[10];
    const float* as2 = (const float*)d_in[11];
    const float* ad2 = (const float*)d_in[12];
    const float* ae2 = (const float*)d_in[13];
    const float* b2 = (const float*)d_in[14];
    float* out = (float*)d_out;

    char* ws = (char*)d_ws;
    size_t off = 0;
    auto alloc = [&](size_t bytes) -> void* {
        void* p = ws + off;
        off += (bytes + 255) & ~(size_t)255;
        return p;
    };
    int* cnt = (int*)alloc((size_t)N_NODES * 4);
    int* cursor = (int*)alloc((size_t)N_NODES * 4);
    int* csr_off = (int*)alloc(((size_t)N_NODES + 1) * 4);
    int* csr_eid = (int*)alloc((size_t)N_EDGES * 4);
    int* csr_src = (int*)alloc((size_t)N_EDGES * 4);
    int* epos = (int*)alloc((size_t)N_EDGES * 4);
    int* bsums = (int*)alloc(256 * 4);
    int* bsums2 = (int*)alloc(256 * 4);
    _Float16* x16 = (_Float16*)alloc((size_t)N_NODES * 128 * 2);
    _Float16* H16 = (_Float16*)alloc((size_t)N_NODES * 128 * 2);
    _Float16* h1_16 = (_Float16*)alloc((size_t)N_NODES * 64 * 2);
    float* a_src = (float*)alloc((size_t)N_NODES * 2 * 4);
    float* a_dst = (float*)alloc((size_t)N_NODES * 2 * 4);
    float2* exl_csr = (float2*)alloc((size_t)N_EDGES * 8);
    float2* exl_self = (float2*)alloc((size_t)N_NODES * 8);
    float4* a_e4 = (float4*)alloc((size_t)N_EDGES * 16);
    float4* ae_self4 = (float4*)alloc((size_t)N_NODES * 16);
    float* w_e1 = (float*)alloc(32 * 4);
    float* w_e2 = (float*)alloc(32 * 4);

    const int nb = (N_NODES + 255) / 256;

    // ---- CSR + shared edge precompute ----
    hipMemsetAsync(cnt, 0, (size_t)N_NODES * 4, stream);
    count_kernel<<<(N_EDGES + 255) / 256, 256, 0, stream>>>(ei, cnt);
    scan_block_kernel<<<nb, 256, 0, stream>>>(cnt, cursor, bsums, N_NODES);
    scan_block_kernel<<<1, 256, 0, stream>>>(bsums, bsums2, nullptr, nb);
    scan_add_kernel<<<nb, 256, 0, stream>>>(cursor, bsums2, csr_off, cursor, N_NODES, N_EDGES);
    scatter_kernel<<<(N_EDGES + 255) / 256, 256, 0, stream>>>(ei, cursor, csr_eid, csr_src, epos);
    we_kernel<<<1, 64, 0, stream>>>(We1, ae1, w_e1);
    we_kernel<<<1, 64, 0, stream>>>(We2, ae2, w_e2);
    edge_dot_kernel<<<(N_EDGES + 255) / 256, 256, 0, stream>>>(edge_attr, w_e1, w_e2, a_e4);
    self_mean_kernel<<<(N_NODES + 255) / 256, 256, 0, stream>>>(a_e4, csr_off, csr_eid, ae_self4);
    cast_f16_kernel<<<(N_NODES * 128 / 8 + 255) / 256, 256, 0, stream>>>(x, x16, N_NODES * 128 / 8);

    const int nodeWaveBlocks = (N_NODES * 64 + 255) / 256;
    const int edgeBlocks = (N_EDGES + N_NODES + 255) / 256;
    const int gemmBlocks = (N_NODES + 63) / 64;

    // ---- layer 1: IN=128 -> HID=64, H=2, relu ----
    gemm_att_kernel<128><<<gemmBlocks, 256, 0, stream>>>(x16, W1, as1, ad1, H16,
                                                         (float2*)a_src, (float2*)a_dst, N_NODES);
    edge_logit_kernel<<<edgeBlocks, 256, 0, stream>>>(ei, (const float2*)a_e4, (const float2*)ae_self4, 0,
                                                      (const float2*)a_src, (const float2*)a_dst,
                                                      epos, exl_csr, exl_self);
    aggregate_kernel<<<nodeWaveBlocks, 256, 0, stream>>>(csr_off, csr_src, exl_csr, exl_self, H16, b1,
                                                         nullptr, h1_16, 1);

    // ---- layer 2: HID=64 -> OUT=64, H=2, no relu ----
    gemm_att_kernel<64><<<gemmBlocks, 256, 0, stream>>>(h1_16, W2, as2, ad2, H16,
                                                        (float2*)a_src, (float2*)a_dst, N_NODES);
    edge_logit_kernel<<<edgeBlocks, 256, 0, stream>>>(ei, (const float2*)a_e4, (const float2*)ae_self4, 1,
                                                      (const float2*)a_src, (const float2*)a_dst,
                                                      epos, exl_csr, exl_self);
    aggregate_kernel<<<nodeWaveBlocks, 256, 0, stream>>>(csr_off, csr_src, exl_csr, exl_self, H16, b2,
                                                         out, nullptr, 0);
}

// Round 8
// 220.118 us; speedup vs baseline: 1.7357x; 1.4020x over previous
//
#include <hip/hip_runtime.h>

#define N_NODES 50000
#define N_EDGES 800000
#define EDIM 16
#define NEG_SLOPE 0.2f

typedef _Float16 f16x8 __attribute__((ext_vector_type(8)));
typedef _Float16 f16x2 __attribute__((ext_vector_type(2)));
typedef float f32x4 __attribute__((ext_vector_type(4)));

// ============================ CSR build ============================
__global__ void count_kernel(const int* __restrict__ ei, int* __restrict__ cnt) {
    int e = blockIdx.x * blockDim.x + threadIdx.x;
    if (e < N_EDGES) atomicAdd(&cnt[ei[N_EDGES + e]], 1);
}

__global__ void scan_block_kernel(const int* __restrict__ in, int* __restrict__ excl,
                                  int* __restrict__ bsums, int n) {
    __shared__ int sh[256];
    int tid = threadIdx.x;
    int gid = blockIdx.x * 256 + tid;
    int v = (gid < n) ? in[gid] : 0;
    sh[tid] = v;
    __syncthreads();
    for (int off = 1; off < 256; off <<= 1) {
        int t = (tid >= off) ? sh[tid - off] : 0;
        __syncthreads();
        sh[tid] += t;
        __syncthreads();
    }
    if (gid < n) excl[gid] = sh[tid] - v;
    if (bsums != nullptr && tid == 255) bsums[blockIdx.x] = sh[tid];
}

__global__ void scan_add_kernel(const int* __restrict__ excl, const int* __restrict__ bs2,
                                int* __restrict__ csr_off, int* __restrict__ cursor,
                                int n, int total) {
    int gid = blockIdx.x * 256 + threadIdx.x;
    if (gid < n) {
        int v = excl[gid] + bs2[gid >> 8];
        csr_off[gid] = v;
        cursor[gid] = v;
    }
    if (gid == 0) csr_off[n] = total;
}

// w_e layout: [0:16) l1h0, [16:32) l1h1, [32:48) l2h0, [48:64) l2h1
__global__ void we2_kernel(const float* __restrict__ We1, const float* __restrict__ ae1,
                           const float* __restrict__ We2, const float* __restrict__ ae2,
                           float* __restrict__ w_e) {
    int idx = threadIdx.x;
    if (idx >= 64) return;
    const float* We = (idx < 32) ? We1 : We2;
    const float* ae = (idx < 32) ? ae1 : ae2;
    int i = idx & 31;
    int h = i >> 4, d = i & 15;
    float s = 0.f;
    for (int c = 0; c < 64; ++c) s += We[d * 128 + h * 64 + c] * ae[h * 64 + c];
    w_e[idx] = s;
}

// scatter + per-edge attention-edge dots (both layers) written directly in CSR order
__global__ void scatter_fused_kernel(const int* __restrict__ ei, const float* __restrict__ edge_attr,
                                     const float* __restrict__ w_e, int* __restrict__ cursor,
                                     int* __restrict__ csr_src,
                                     float2* __restrict__ ae1_csr, float2* __restrict__ ae2_csr) {
    int e = blockIdx.x * blockDim.x + threadIdx.x;
    if (e >= N_EDGES) return;
    int s = ei[e];
    int d = ei[N_EDGES + e];
    float4 dd = make_float4(0.f, 0.f, 0.f, 0.f);
#pragma unroll
    for (int q = 0; q < 4; ++q) {
        float4 v = *reinterpret_cast<const float4*>(edge_attr + (size_t)e * 16 + q * 4);
        float4 wa = *reinterpret_cast<const float4*>(w_e + q * 4);
        float4 wb = *reinterpret_cast<const float4*>(w_e + 16 + q * 4);
        float4 wc = *reinterpret_cast<const float4*>(w_e + 32 + q * 4);
        float4 wd = *reinterpret_cast<const float4*>(w_e + 48 + q * 4);
        dd.x += v.x * wa.x + v.y * wa.y + v.z * wa.z + v.w * wa.w;
        dd.y += v.x * wb.x + v.y * wb.y + v.z * wb.z + v.w * wb.w;
        dd.z += v.x * wc.x + v.y * wc.y + v.z * wc.z + v.w * wc.w;
        dd.w += v.x * wd.x + v.y * wd.y + v.z * wd.z + v.w * wd.w;
    }
    int pos = atomicAdd(&cursor[d], 1);
    csr_src[pos] = s;
    ae1_csr[pos] = make_float2(dd.x, dd.y);
    ae2_csr[pos] = make_float2(dd.z, dd.w);
}

// self-loop edge dot = mean of incoming edges' dots; CSR-contiguous reads
__global__ void self_mean_kernel(const float2* __restrict__ ae1_csr, const float2* __restrict__ ae2_csr,
                                 const int* __restrict__ csr_off,
                                 float2* __restrict__ ae1_self, float2* __restrict__ ae2_self) {
    int n = blockIdx.x * blockDim.x + threadIdx.x;
    if (n >= N_NODES) return;
    int b = csr_off[n], e = csr_off[n + 1];
    float2 s1 = make_float2(0.f, 0.f), s2 = make_float2(0.f, 0.f);
    for (int j = b; j < e; ++j) {
        float2 v1 = ae1_csr[j], v2 = ae2_csr[j];
        s1.x += v1.x; s1.y += v1.y;
        s2.x += v2.x; s2.y += v2.y;
    }
    float inv = 1.f / (float)((e - b) > 0 ? (e - b) : 1);
    ae1_self[n] = make_float2(s1.x * inv, s1.y * inv);
    ae2_self[n] = make_float2(s2.x * inv, s2.y * inv);
}

// ============================ fused MFMA GEMM + attdot ============================
// H = X[M,K](f32, cast to f16) @ W[K,128]. Writes H16 + per-row a_src/a_dst dots.
// Layouts (guide §3, m89/m156): A: row=lane&15, k=8*(lane>>4)+j
//                               B: col=lane&15, k=8*(lane>>4)+j
//                               D: col=lane&15, row=4*(lane>>4)+reg
template <int K>
__global__ __launch_bounds__(256) void gemm_att_kernel(const float* __restrict__ X,
                                                       const float* __restrict__ W,
                                                       const float* __restrict__ as_,
                                                       const float* __restrict__ ad_,
                                                       _Float16* __restrict__ H16,
                                                       float2* __restrict__ a_src,
                                                       float2* __restrict__ a_dst, int M) {
    constexpr int NCH = K / 32;
    __shared__ _Float16 wlds[8 * NCH * 64 * 8];  // [ct][chunk][lane][j]
    const int tid = threadIdx.x;

    for (int idx = tid; idx < K * 128; idx += 256) {
        int k = idx >> 7, c = idx & 127;
        int ct = c >> 4, cl = c & 15;
        int chunk = k >> 5, grp = (k >> 3) & 3, j = k & 7;
        wlds[(((ct * NCH) + chunk) * 64 + (grp * 16 + cl)) * 8 + j] = (_Float16)W[idx];
    }
    __syncthreads();

    const int wv = tid >> 6, lane = tid & 63;
    const int lcol = lane & 15, lgrp = lane >> 4;
    const int row0 = blockIdx.x * 64 + wv * 16;
    int arow = row0 + lcol;
    if (arow >= M) arow = M - 1;
    const float* aptr = X + (size_t)arow * K + lgrp * 8;

    f32x4 acc[8];
#pragma unroll
    for (int ct = 0; ct < 8; ++ct) acc[ct] = (f32x4){0.f, 0.f, 0.f, 0.f};

#pragma unroll
    for (int chunk = 0; chunk < NCH; ++chunk) {
        float4 va = *reinterpret_cast<const float4*>(aptr + chunk * 32);
        float4 vb = *reinterpret_cast<const float4*>(aptr + chunk * 32 + 4);
        f16x8 afrag = {(_Float16)va.x, (_Float16)va.y, (_Float16)va.z, (_Float16)va.w,
                       (_Float16)vb.x, (_Float16)vb.y, (_Float16)vb.z, (_Float16)vb.w};
#pragma unroll
        for (int ct = 0; ct < 8; ++ct) {
            f16x8 bfrag = *reinterpret_cast<const f16x8*>(&wlds[((ct * NCH + chunk) * 64 + lane) * 8]);
            acc[ct] = __builtin_amdgcn_mfma_f32_16x16x32_f16(afrag, bfrag, acc[ct], 0, 0, 0);
        }
    }

    float asv[8], adv[8];
#pragma unroll
    for (int ct = 0; ct < 8; ++ct) {
        asv[ct] = as_[ct * 16 + lcol];
        adv[ct] = ad_[ct * 16 + lcol];
    }

#pragma unroll
    for (int r = 0; r < 4; ++r) {
        int grow = row0 + lgrp * 4 + r;
        float s0 = 0.f, s1 = 0.f, d0 = 0.f, d1 = 0.f;
#pragma unroll
        for (int ct = 0; ct < 8; ++ct) {
            float v = acc[ct][r];
            if (grow < M) H16[(size_t)grow * 128 + ct * 16 + lcol] = (_Float16)v;
            if (ct < 4) { s0 += v * asv[ct]; d0 += v * adv[ct]; }
            else        { s1 += v * asv[ct]; d1 += v * adv[ct]; }
        }
#pragma unroll
        for (int m = 1; m < 16; m <<= 1) {
            s0 += __shfl_xor(s0, m);
            s1 += __shfl_xor(s1, m);
            d0 += __shfl_xor(d0, m);
            d1 += __shfl_xor(d1, m);
        }
        if (lcol == 0 && grow < M) {
            a_src[grow] = make_float2(s0, s1);
            a_dst[grow] = make_float2(d0, d1);
        }
    }
}

// ============================ fused logit + aggregate ============================
// one wave per dst node; lane = half2 (2 channels of one head: lanes<32 head0, >=32 head1).
// Computes edge logits in the chunk header (a_dst[n] is wave-uniform), exp in-register,
// 1x4B gather per edge-lane, depth-4 static prefetch, head-combine via shfl_xor(32).
#define AGG_STAGE(P, TT)                                                          \
    do {                                                                          \
        float e0_ = __shfl(exv.x, (TT));                                          \
        float e1_ = __shfl(exv.y, (TT));                                          \
        float exu_ = hi ? e1_ : e0_;                                              \
        den += exu_;                                                              \
        acc0 = fmaf(exu_, (float)P.x, acc0);                                      \
        acc1 = fmaf(exu_, (float)P.y, acc1);                                      \
        int sn_ = __shfl(sv, ((TT) + 4) & 63);                                    \
        P = *reinterpret_cast<const f16x2*>(hbase + ((size_t)(unsigned)sn_ << 8)); \
    } while (0)

__global__ void aggregate_kernel(const int* __restrict__ csr_off, const int* __restrict__ csr_src,
                                 const float2* __restrict__ ae_csr, const float2* __restrict__ ae_self,
                                 const float2* __restrict__ a_src, const float2* __restrict__ a_dst,
                                 const _Float16* __restrict__ H16, const float* __restrict__ bias,
                                 float* __restrict__ outp, int do_relu) {
    int wid = (blockIdx.x * blockDim.x + threadIdx.x) >> 6;
    int lane = threadIdx.x & 63;
    if (wid >= N_NODES) return;
    const int n = wid;
    const bool hi = lane >= 32;
    const char* hbase = reinterpret_cast<const char*>(H16) + lane * 4;

    // self-loop logit (wave-uniform inputs)
    float2 adn = a_dst[n];
    float2 asn = a_src[n];
    float2 aes = ae_self[n];
    float l0 = asn.x + adn.x + aes.x;
    float l1 = asn.y + adn.y + aes.y;
    l0 = (l0 > 0.f) ? l0 : NEG_SLOPE * l0;
    l1 = (l1 > 0.f) ? l1 : NEG_SLOPE * l1;
    float exs = hi ? __expf(l1) : __expf(l0);

    f16x2 hs = *reinterpret_cast<const f16x2*>(hbase + ((size_t)(unsigned)n << 8));
    float den = exs;
    float acc0 = exs * (float)hs.x;
    float acc1 = exs * (float)hs.y;

    int b = csr_off[n], e = csr_off[n + 1];
    for (int base = b; base < e; base += 64) {
        int j = base + lane;
        bool act = j < e;
        int sv = act ? csr_src[j] : n;
        float2 exv = make_float2(0.f, 0.f);
        if (act) {
            float2 ael = ae_csr[j];
            float2 asv = a_src[sv];
            float q0 = asv.x + adn.x + ael.x;
            float q1 = asv.y + adn.y + ael.y;
            q0 = (q0 > 0.f) ? q0 : NEG_SLOPE * q0;
            q1 = (q1 > 0.f) ? q1 : NEG_SLOPE * q1;
            exv = make_float2(__expf(q0), __expf(q1));
        }
        int m = e - base;
        if (m > 64) m = 64;
        int mq = (m + 3) & ~3;
        f16x2 p0, p1, p2, p3;
        int s;
        s = __shfl(sv, 0); p0 = *reinterpret_cast<const f16x2*>(hbase + ((size_t)(unsigned)s << 8));
        s = __shfl(sv, 1); p1 = *reinterpret_cast<const f16x2*>(hbase + ((size_t)(unsigned)s << 8));
        s = __shfl(sv, 2); p2 = *reinterpret_cast<const f16x2*>(hbase + ((size_t)(unsigned)s << 8));
        s = __shfl(sv, 3); p3 = *reinterpret_cast<const f16x2*>(hbase + ((size_t)(unsigned)s << 8));
        for (int t = 0; t < mq; t += 4) {
            AGG_STAGE(p0, t);
            AGG_STAGE(p1, t + 1);
            AGG_STAGE(p2, t + 2);
            AGG_STAGE(p3, t + 3);
        }
    }

    float inv = 1.f / (den + 1e-16f);
    float r0 = acc0 * inv;
    float r1 = acc1 * inv;
    // combine heads: lane^32 holds the other head's same 2 channels
    float o0 = 0.5f * (r0 + __shfl_xor(r0, 32));
    float o1 = 0.5f * (r1 + __shfl_xor(r1, 32));
    if (!hi) {
        float2 bv = *reinterpret_cast<const float2*>(bias + 2 * lane);
        o0 += bv.x;
        o1 += bv.y;
        if (do_relu) { o0 = fmaxf(o0, 0.f); o1 = fmaxf(o1, 0.f); }
        *reinterpret_cast<float2*>(outp + (size_t)n * 64 + 2 * lane) = make_float2(o0, o1);
    }
}

// ============================ launch ============================
extern "C" void kernel_launch(void* const* d_in, const int* in_sizes, int n_in,
                              void* d_out, int out_size, void* d_ws, size_t ws_size,
                              hipStream_t stream) {
    const float* x = (const float*)d_in[0];
    const int* ei = (const int*)d_in[1];
    const float* edge_attr = (const float*)d_in[2];
    const float* W1 = (const float*)d_in[3];
    const float* We1 = (const float*)d_in[4];
    const float* as1 = (const float*)d_in[5];
    const float* ad1 = (const float*)d_in[6];
    const float* ae1 = (const float*)d_in[7];
    const float* b1 = (const float*)d_in[8];
    const float* W2 = (const float*)d_in[9];
    const float* We2 = (const float*)d_in[10];
    const float* as2 = (const float*)d_in[11];
    const float* ad2 = (const float*)d_in[12];
    const float* ae2 = (const float*)d_in[13];
    const float* b2 = (const float*)d_in[14];
    float* out = (float*)d_out;

    char* ws = (char*)d_ws;
    size_t off = 0;
    auto alloc = [&](size_t bytes) -> void* {
        void* p = ws + off;
        off += (bytes + 255) & ~(size_t)255;
        return p;
    };
    int* cnt = (int*)alloc((size_t)N_NODES * 4);
    int* cursor = (int*)alloc((size_t)N_NODES * 4);
    int* csr_off = (int*)alloc(((size_t)N_NODES + 1) * 4);
    int* csr_src = (int*)alloc((size_t)N_EDGES * 4);
    int* bsums = (int*)alloc(256 * 4);
    int* bsums2 = (int*)alloc(256 * 4);
    float2* ae1_csr = (float2*)alloc((size_t)N_EDGES * 8);
    float2* ae2_csr = (float2*)alloc((size_t)N_EDGES * 8);
    float2* ae1_self = (float2*)alloc((size_t)N_NODES * 8);
    float2* ae2_self = (float2*)alloc((size_t)N_NODES * 8);
    _Float16* H16 = (_Float16*)alloc((size_t)N_NODES * 128 * 2);
    float* h1 = (float*)alloc((size_t)N_NODES * 64 * 4);
    float* a_src = (float*)alloc((size_t)N_NODES * 2 * 4);
    float* a_dst = (float*)alloc((size_t)N_NODES * 2 * 4);
    float* w_e = (float*)alloc(64 * 4);

    const int nb = (N_NODES + 255) / 256;

    // ---- CSR + fused edge precompute ----
    hipMemsetAsync(cnt, 0, (size_t)N_NODES * 4, stream);
    count_kernel<<<(N_EDGES + 255) / 256, 256, 0, stream>>>(ei, cnt);
    scan_block_kernel<<<nb, 256, 0, stream>>>(cnt, cursor, bsums, N_NODES);
    scan_block_kernel<<<1, 256, 0, stream>>>(bsums, bsums2, nullptr, nb);
    scan_add_kernel<<<nb, 256, 0, stream>>>(cursor, bsums2, csr_off, cursor, N_NODES, N_EDGES);
    we2_kernel<<<1, 64, 0, stream>>>(We1, ae1, We2, ae2, w_e);
    scatter_fused_kernel<<<(N_EDGES + 255) / 256, 256, 0, stream>>>(ei, edge_attr, w_e, cursor,
                                                                    csr_src, ae1_csr, ae2_csr);
    self_mean_kernel<<<(N_NODES + 255) / 256, 256, 0, stream>>>(ae1_csr, ae2_csr, csr_off,
                                                                ae1_self, ae2_self);

    const int nodeWaveBlocks = (N_NODES * 64 + 255) / 256;
    const int gemmBlocks = (N_NODES + 63) / 64;

    // ---- layer 1: IN=128 -> HID=64, H=2, relu ----
    gemm_att_kernel<128><<<gemmBlocks, 256, 0, stream>>>(x, W1, as1, ad1, H16,
                                                         (float2*)a_src, (float2*)a_dst, N_NODES);
    aggregate_kernel<<<nodeWaveBlocks, 256, 0, stream>>>(csr_off, csr_src, ae1_csr, ae1_self,
                                                         (const float2*)a_src, (const float2*)a_dst,
                                                         H16, b1, h1, 1);

    // ---- layer 2: HID=64 -> OUT=64, H=2, no relu ----
    gemm_att_kernel<64><<<gemmBlocks, 256, 0, stream>>>(h1, W2, as2, ad2, H16,
                                                        (float2*)a_src, (float2*)a_dst, N_NODES);
    aggregate_kernel<<<nodeWaveBlocks, 256, 0, stream>>>(csr_off, csr_src, ae2_csr, ae2_self,
                                                         (const float2*)a_src, (const float2*)a_dst,
                                                         H16, b2, out, 0);
}